// Round 4
// baseline (291.607 us; speedup 1.0000x reference)
//
#include <hip/hip_runtime.h>

#define TSEQ 4096
#define CDIM 1024
#define DHEAD 64

typedef __bf16 bf16x8 __attribute__((ext_vector_type(8)));
typedef float f32x4 __attribute__((ext_vector_type(4)));

#define KCHUNK 128          // f32 cols per chunk
#define NCHUNK (CDIM / KCHUNK)

// ---------------- W pre-convert: f32 [3][64][1024] -> bf16 ----------------
// One-shot 384KB kernel so proj reads W as bf16x8 fragments directly (no
// per-lane cvt of W, which would be ~128 VALU ops/lane/chunk inline).
__global__ __launch_bounds__(256) void wconv_kernel(
    const float* __restrict__ wq, const float* __restrict__ wk,
    const float* __restrict__ wv, __bf16* __restrict__ Wb)
{
  const int t = blockIdx.x * 256 + threadIdx.x;   // 24576 threads
  const int idx = t * 8;                          // elem index in [0, 196608)
  const int pid = idx >> 16;                      // 65536 elems per matrix
  const float* __restrict__ src = (pid == 0) ? wq : ((pid == 1) ? wk : wv);
  const int off = idx & 65535;
  f32x4 a = *(const f32x4*)(src + off);
  f32x4 b = *(const f32x4*)(src + off + 4);
  ushort4 lo, hi;
  lo.x = __builtin_bit_cast(unsigned short, (__bf16)a[0]);
  lo.y = __builtin_bit_cast(unsigned short, (__bf16)a[1]);
  lo.z = __builtin_bit_cast(unsigned short, (__bf16)a[2]);
  lo.w = __builtin_bit_cast(unsigned short, (__bf16)a[3]);
  hi.x = __builtin_bit_cast(unsigned short, (__bf16)b[0]);
  hi.y = __builtin_bit_cast(unsigned short, (__bf16)b[1]);
  hi.z = __builtin_bit_cast(unsigned short, (__bf16)b[2]);
  hi.w = __builtin_bit_cast(unsigned short, (__bf16)b[3]);
  *(ushort4*)(Wb + idx) = lo;
  *(ushort4*)(Wb + idx + 4) = hi;
}

// ---------------- Projection: out[m,n] = sum_c emb[m,c] * W[n,c] ----------------
// LDS-FREE REWRITE (r4). r3 rocprof: proj 82us, VGPR=52 (r2's reg pipeline never
// materialized), Occ 25% (grid-limited 3 blocks/CU), MfmaUtil 2.8%, barriers +
// single-buffered LDS serialized staging. Key insight: the A tile had ZERO
// cross-wave reuse (each wave staged/read its own 16 rows) -> stage nothing.
// Each lane (g,c) loads its A-row fragments straight from global (32B/lane per
// ks), cvt f32->bf16 inline; W is read as bf16x8 fragments (pre-converted by
// wconv) -- per-chunk W slice is 32KB -> L1-resident after the first wave.
// No LDS, no barriers: waves free-run; explicit 3-buffer distance-2 A-prefetch
// pipeline (all static indices) keeps ~24 loads in flight.
// Q,K stored [B*T,64] bf16, V stored transposed Vt[b][64][T] bf16.
__global__ __launch_bounds__(256) void proj_kernel(
    const float* __restrict__ qe, const float* __restrict__ ke,
    const float* __restrict__ ve, const __bf16* __restrict__ Wb,
    __bf16* __restrict__ Qo, __bf16* __restrict__ Ko, __bf16* __restrict__ Vto)
{
  const int pid = blockIdx.y;
  const float* __restrict__ emb = (pid == 0) ? qe : ((pid == 1) ? ke : ve);
  const __bf16* __restrict__ W = Wb + (size_t)pid * DHEAD * CDIM;

  const int wave = threadIdx.x >> 6;
  const int lane = threadIdx.x & 63;
  const int g = lane >> 4, c = lane & 15;
  const int m0 = blockIdx.x * 64 + wave * 16;   // wave's 16 output rows

  const float* __restrict__ arow = emb + (size_t)(m0 + c) * CDIM + g * 8;
  const __bf16* __restrict__ wbase = W + (size_t)c * CDIM + g * 8;

  f32x4 acc[4];
#pragma unroll
  for (int n = 0; n < 4; ++n) acc[n] = (f32x4){0.f, 0.f, 0.f, 0.f};

  auto loadA = [&](f32x4* L, f32x4* H, int ch) {
#pragma unroll
    for (int ks = 0; ks < 4; ++ks) {
      const float* p = arow + ch * KCHUNK + ks * 32;
      L[ks] = *(const f32x4*)(p);
      H[ks] = *(const f32x4*)(p + 4);
    }
  };
  auto compute = [&](const f32x4* L, const f32x4* H, int ch) {
#pragma unroll
    for (int ks = 0; ks < 4; ++ks) {
      bf16x8 af;
      af[0] = (__bf16)L[ks][0];
      af[1] = (__bf16)L[ks][1];
      af[2] = (__bf16)L[ks][2];
      af[3] = (__bf16)L[ks][3];
      af[4] = (__bf16)H[ks][0];
      af[5] = (__bf16)H[ks][1];
      af[6] = (__bf16)H[ks][2];
      af[7] = (__bf16)H[ks][3];
      const __bf16* wp = wbase + ch * KCHUNK + ks * 32;
#pragma unroll
      for (int n = 0; n < 4; ++n) {
        bf16x8 wf = *(const bf16x8*)(wp + (size_t)n * 16 * CDIM);
        acc[n] = __builtin_amdgcn_mfma_f32_16x16x32_bf16(af, wf, acc[n], 0, 0, 0);
      }
    }
  };

  // 3-buffer, distance-2 prefetch pipeline; full unroll -> static buffer idx
  f32x4 L[3][4], H[3][4];
  loadA(L[0], H[0], 0);
  loadA(L[1], H[1], 1);
  loadA(L[2], H[2], 2);
#pragma unroll
  for (int ch = 0; ch < NCHUNK; ++ch) {
    compute(L[ch % 3], H[ch % 3], ch);
    if (ch + 3 < NCHUNK) loadA(L[ch % 3], H[ch % 3], ch + 3);
  }

  // C/D layout: col = lane&15 (=c -> n*16+c), row = (lane>>4)*4 + reg (= m0+4g+r)
  if (pid < 2) {
    __bf16* __restrict__ dst = (pid == 0) ? Qo : Ko;
#pragma unroll
    for (int n = 0; n < 4; ++n)
#pragma unroll
      for (int r = 0; r < 4; ++r)
        dst[(size_t)(m0 + g * 4 + r) * DHEAD + n * 16 + c] = (__bf16)acc[n][r];
  } else {
    // Vt[b][v][t]: regs 0..3 are 4 consecutive t -> pack one 8B store
    const int t0 = m0 + g * 4;
    const int bb = t0 >> 12;        // 4096 rows per batch, blocks never straddle
    const int tl = t0 & (TSEQ - 1);
#pragma unroll
    for (int n = 0; n < 4; ++n) {
      const int v = n * 16 + c;
      ushort4 pk;
      pk.x = __builtin_bit_cast(unsigned short, (__bf16)acc[n][0]);
      pk.y = __builtin_bit_cast(unsigned short, (__bf16)acc[n][1]);
      pk.z = __builtin_bit_cast(unsigned short, (__bf16)acc[n][2]);
      pk.w = __builtin_bit_cast(unsigned short, (__bf16)acc[n][3]);
      *(ushort4*)(Vto + ((size_t)bb * DHEAD + v) * TSEQ + tl) = pk;
    }
  }
}

// ---------------- Causal flash attention, static-max softmax ----------------
// One block = 16 q-rows, 8 waves split the s-tiles; two independent s-tile
// chains per iteration (st, st+8) for in-wave ILP. (r3; attn < 82us now.)
// Static m=0 is safe: |scores| < ~1 after 1/32 scale, exp2 cannot overflow.
// Row-sum l computed with a ones-vector MFMA (lands in same C-layout rows as O).
// OUTPUT IS FLOAT32 (reference output dtype).
#define NWAVE 8

__global__ __launch_bounds__(512) void attn_kernel(
    const __bf16* __restrict__ Q, const __bf16* __restrict__ K,
    const __bf16* __restrict__ Vt, float* __restrict__ out)
{
  __shared__ __bf16 Plds[NWAVE][16][72];   // per-wave P (C-layout -> A-layout round trip)
  __shared__ float Om[NWAVE][16][65];      // per-wave partial O for the merge
  __shared__ float La[NWAVE][16];          // per-wave partial row-sums

  const int b = blockIdx.y;
  const int tile = (int)gridDim.x - 1 - (int)blockIdx.x;  // big tiles first
  const int q0 = tile * 16;
  const int wave = threadIdx.x >> 6;
  const int lane = threadIdx.x & 63;
  const int g = lane >> 4, c = lane & 15;

  const __bf16* Qb = Q + (size_t)b * TSEQ * DHEAD;
  const __bf16* Kb = K + (size_t)b * TSEQ * DHEAD;
  const __bf16* Vb = Vt + (size_t)b * DHEAD * TSEQ;

  bf16x8 aq0 = *(const bf16x8*)(Qb + (size_t)(q0 + c) * DHEAD + g * 8);
  bf16x8 aq1 = *(const bf16x8*)(Qb + (size_t)(q0 + c) * DHEAD + 32 + g * 8);

  bf16x8 ones;
#pragma unroll
  for (int j = 0; j < 8; ++j) ones[j] = (__bf16)1.0f;

  f32x4 o[4];
#pragma unroll
  for (int n = 0; n < 4; ++n) o[n] = (f32x4){0.f, 0.f, 0.f, 0.f};
  f32x4 lacc = (f32x4){0.f, 0.f, 0.f, 0.f};

  const float kScale = 0.04508422f;  // (1/32) * log2(e)
  const int nt = (q0 + 16 + 63) >> 6;

  for (int st = wave; st < nt; st += 2 * NWAVE) {
    const int s0A = st * 64;
    const int stB = st + NWAVE;
    const bool hasB = stB < nt;              // wave-uniform
    const int s0B = stB * 64;

    // ---- issue BOTH chains' K loads up front (16 loads in flight) ----
    bf16x8 ka0[4], ka1[4], kb0[4], kb1[4];
#pragma unroll
    for (int n = 0; n < 4; ++n) {
      const __bf16* kp = Kb + (size_t)(s0A + n * 16 + c) * DHEAD + g * 8;
      ka0[n] = *(const bf16x8*)(kp);
      ka1[n] = *(const bf16x8*)(kp + 32);
    }
    if (hasB) {
#pragma unroll
      for (int n = 0; n < 4; ++n) {
        const __bf16* kp = Kb + (size_t)(s0B + n * 16 + c) * DHEAD + g * 8;
        kb0[n] = *(const bf16x8*)(kp);
        kb1[n] = *(const bf16x8*)(kp + 32);
      }
    }

    // ---- chain A: QK ----
    f32x4 sA[4];
#pragma unroll
    for (int n = 0; n < 4; ++n) {
      f32x4 z = (f32x4){0.f, 0.f, 0.f, 0.f};
      z = __builtin_amdgcn_mfma_f32_16x16x32_bf16(aq0, ka0[n], z, 0, 0, 0);
      sA[n] = __builtin_amdgcn_mfma_f32_16x16x32_bf16(aq1, ka1[n], z, 0, 0, 0);
    }
    // ---- hoisted V loads A (latency hides under exp/DS below) ----
    bf16x8 va0[4], va1[4];
#pragma unroll
    for (int n = 0; n < 4; ++n) {
      const __bf16* vp = Vb + (size_t)(n * 16 + c) * TSEQ + s0A + g * 8;
      va0[n] = *(const bf16x8*)(vp);
      va1[n] = *(const bf16x8*)(vp + 32);
    }
    // ---- exp + DS-write A ----
#pragma unroll
    for (int n = 0; n < 4; ++n) {
      const int sidx = s0A + n * 16 + c;
#pragma unroll
      for (int r = 0; r < 4; ++r) {
        const int qidx = q0 + g * 4 + r;
        float p = (sidx <= qidx) ? __builtin_amdgcn_exp2f(sA[n][r] * kScale) : 0.f;
        Plds[wave][g * 4 + r][n * 16 + c] = (__bf16)p;
      }
    }

    // ---- chain B: QK (K arrived while A ran) + hoisted V loads B ----
    f32x4 sB[4];
    bf16x8 vb0[4], vb1[4];
    if (hasB) {
#pragma unroll
      for (int n = 0; n < 4; ++n) {
        f32x4 z = (f32x4){0.f, 0.f, 0.f, 0.f};
        z = __builtin_amdgcn_mfma_f32_16x16x32_bf16(aq0, kb0[n], z, 0, 0, 0);
        sB[n] = __builtin_amdgcn_mfma_f32_16x16x32_bf16(aq1, kb1[n], z, 0, 0, 0);
      }
#pragma unroll
      for (int n = 0; n < 4; ++n) {
        const __bf16* vp = Vb + (size_t)(n * 16 + c) * TSEQ + s0B + g * 8;
        vb0[n] = *(const bf16x8*)(vp);
        vb1[n] = *(const bf16x8*)(vp + 32);
      }
    }

    // ---- DS-read A, rowsum A ----
    bf16x8 p0A = *(const bf16x8*)(&Plds[wave][c][g * 8]);
    bf16x8 p1A = *(const bf16x8*)(&Plds[wave][c][32 + g * 8]);
    lacc = __builtin_amdgcn_mfma_f32_16x16x32_bf16(p0A, ones, lacc, 0, 0, 0);
    lacc = __builtin_amdgcn_mfma_f32_16x16x32_bf16(p1A, ones, lacc, 0, 0, 0);

    // ---- exp + DS-write B (aliases A's reads -> ordered after them) ----
    if (hasB) {
#pragma unroll
      for (int n = 0; n < 4; ++n) {
        const int sidx = s0B + n * 16 + c;
#pragma unroll
        for (int r = 0; r < 4; ++r) {
          const int qidx = q0 + g * 4 + r;
          float p = (sidx <= qidx) ? __builtin_amdgcn_exp2f(sB[n][r] * kScale) : 0.f;
          Plds[wave][g * 4 + r][n * 16 + c] = (__bf16)p;
        }
      }
    }

    // ---- PV A (V arrived during exp/DS) ----
#pragma unroll
    for (int n = 0; n < 4; ++n) {
      o[n] = __builtin_amdgcn_mfma_f32_16x16x32_bf16(p0A, va0[n], o[n], 0, 0, 0);
      o[n] = __builtin_amdgcn_mfma_f32_16x16x32_bf16(p1A, va1[n], o[n], 0, 0, 0);
    }

    // ---- DS-read B, rowsum B, PV B ----
    if (hasB) {
      bf16x8 p0B = *(const bf16x8*)(&Plds[wave][c][g * 8]);
      bf16x8 p1B = *(const bf16x8*)(&Plds[wave][c][32 + g * 8]);
      lacc = __builtin_amdgcn_mfma_f32_16x16x32_bf16(p0B, ones, lacc, 0, 0, 0);
      lacc = __builtin_amdgcn_mfma_f32_16x16x32_bf16(p1B, ones, lacc, 0, 0, 0);
#pragma unroll
      for (int n = 0; n < 4; ++n) {
        o[n] = __builtin_amdgcn_mfma_f32_16x16x32_bf16(p0B, vb0[n], o[n], 0, 0, 0);
        o[n] = __builtin_amdgcn_mfma_f32_16x16x32_bf16(p1B, vb1[n], o[n], 0, 0, 0);
      }
    }
  }

  // write per-wave partials (static max => plain sums merge)
#pragma unroll
  for (int n = 0; n < 4; ++n)
#pragma unroll
    for (int r = 0; r < 4; ++r)
      Om[wave][g * 4 + r][n * 16 + c] = o[n][r];
  if (c == 0) {
#pragma unroll
    for (int r = 0; r < 4; ++r) La[wave][g * 4 + r] = lacc[r];
  }
  __syncthreads();

  // f32 output: 512 threads x (1 row x 2 cols) = 16 rows x 64 cols
  const int tid = threadIdx.x;
  const int q = tid >> 5;
  const int c2 = (tid & 31) * 2;
  float l = 0.f;
#pragma unroll
  for (int w = 0; w < NWAVE; ++w) l += La[w][q];
  float s0 = 0.f, s1 = 0.f;
#pragma unroll
  for (int w = 0; w < NWAVE; ++w) {
    s0 += Om[w][q][c2];
    s1 += Om[w][q][c2 + 1];
  }
  const float inv = 1.0f / l;
  float2 r;
  r.x = s0 * inv;
  r.y = s1 * inv;
  *(float2*)(out + ((size_t)b * TSEQ + q0 + q) * DHEAD + c2) = r;
}

extern "C" void kernel_launch(void* const* d_in, const int* in_sizes, int n_in,
                              void* d_out, int out_size, void* d_ws, size_t ws_size,
                              hipStream_t stream) {
  const float* qe = (const float*)d_in[0];
  const float* ke = (const float*)d_in[1];
  const float* ve = (const float*)d_in[2];
  const float* wq = (const float*)d_in[3];
  const float* wk = (const float*)d_in[4];
  const float* wv = (const float*)d_in[5];

  __bf16* Qw  = (__bf16*)d_ws;
  __bf16* Kw  = Qw + (size_t)4 * TSEQ * DHEAD;
  __bf16* Vtw = Kw + (size_t)4 * TSEQ * DHEAD;
  __bf16* Wb  = Vtw + (size_t)4 * TSEQ * DHEAD;   // 3*64*1024 bf16 = 384KB

  wconv_kernel<<<dim3(96), dim3(256), 0, stream>>>(wq, wk, wv, Wb);

  dim3 g1(4 * TSEQ / 64, 3), b1(256);
  proj_kernel<<<g1, b1, 0, stream>>>(qe, ke, ve, Wb, Qw, Kw, Vtw);

  dim3 g2(TSEQ / 16, 4), b2(512);
  attn_kernel<<<g2, b2, 0, stream>>>(Qw, Kw, Vtw, (float*)d_out);
}

// Round 5
// 279.773 us; speedup vs baseline: 1.0423x; 1.0423x over previous
//
#include <hip/hip_runtime.h>

#define TSEQ 4096
#define CDIM 1024
#define DHEAD 64

typedef __bf16 bf16x8 __attribute__((ext_vector_type(8)));
typedef float f32x4 __attribute__((ext_vector_type(4)));

// ---------------- W pre-convert: f32 [3][64][1024] -> bf16 ----------------
__global__ __launch_bounds__(256) void wconv_kernel(
    const float* __restrict__ wq, const float* __restrict__ wk,
    const float* __restrict__ wv, __bf16* __restrict__ Wb)
{
  const int t = blockIdx.x * 256 + threadIdx.x;   // 24576 threads
  const int idx = t * 8;                          // elem index in [0, 196608)
  const int pid = idx >> 16;                      // 65536 elems per matrix
  const float* __restrict__ src = (pid == 0) ? wq : ((pid == 1) ? wk : wv);
  const int off = idx & 65535;
  f32x4 a = *(const f32x4*)(src + off);
  f32x4 b = *(const f32x4*)(src + off + 4);
  ushort4 lo, hi;
  lo.x = __builtin_bit_cast(unsigned short, (__bf16)a[0]);
  lo.y = __builtin_bit_cast(unsigned short, (__bf16)a[1]);
  lo.z = __builtin_bit_cast(unsigned short, (__bf16)a[2]);
  lo.w = __builtin_bit_cast(unsigned short, (__bf16)a[3]);
  hi.x = __builtin_bit_cast(unsigned short, (__bf16)b[0]);
  hi.y = __builtin_bit_cast(unsigned short, (__bf16)b[1]);
  hi.z = __builtin_bit_cast(unsigned short, (__bf16)b[2]);
  hi.w = __builtin_bit_cast(unsigned short, (__bf16)b[3]);
  *(ushort4*)(Wb + idx) = lo;
  *(ushort4*)(Wb + idx + 4) = hi;
}

// ---------------- Projection: out[m,n] = sum_c emb[m,c] * W[n,c] ----------------
// r5: ASYNC-STAGED (global_load_lds) double-buffered chunk pipeline.
// History: r3 LDS+reg-prefetch 82us (VGPR 52 - compiler sank the prefetch);
// r4 LDS-free reg pipeline 95us (VGPR 44 - sank it again). Lesson: hipcc will
// not keep VGPR-destination global loads in flight across compute. Fix: width-16
// global_load_lds (fire-and-forget, no VGPR dest, cannot be sunk); latency is
// collected only at the vmcnt drain before the per-chunk barrier, overlapped
// with other resident blocks (>=3 blocks/CU). A staged as raw f32 (cvt at
// fragment read); W read global-direct as bf16 (8KB/chunk slice, L1-hot).
// gload_lds needs a LINEAR LDS dest -> bank fix via BOTH-SIDES 16B-slot XOR
// swizzle (col ^= (row&7)<<4): pre-swizzled GLOBAL source + same XOR on read
// (rule: swizzle both sides or neither). 2 buffers x 16KB = 32KB LDS.
// Q,K stored [B*T,64] bf16, V stored transposed Vt[b][64][T] bf16.
#define PKCH 64                  // f32 cols per chunk
#define PNCH (CDIM / PKCH)       // 16 chunks

__global__ __launch_bounds__(256) void proj_kernel(
    const float* __restrict__ qe, const float* __restrict__ ke,
    const float* __restrict__ ve, const __bf16* __restrict__ Wb,
    __bf16* __restrict__ Qo, __bf16* __restrict__ Ko, __bf16* __restrict__ Vto)
{
  __shared__ __align__(16) float Abuf[2][64 * PKCH];   // 2 x 16KB, LINEAR

  const int pid = blockIdx.y;
  const float* __restrict__ emb = (pid == 0) ? qe : ((pid == 1) ? ke : ve);
  const __bf16* __restrict__ W = Wb + (size_t)pid * DHEAD * CDIM;

  const int wave = threadIdx.x >> 6;
  const int lane = threadIdx.x & 63;
  const int g = lane >> 4, c = lane & 15;
  const int bm0 = blockIdx.x * 64;
  const int m0 = bm0 + wave * 16;

  // ---- staging geometry: 16 x 1KB insts/chunk, 4 per wave.
  // inst j: LDS bytes [(wave*4+j)*1024, +1024) = rows [(wave*4+j)*4, +4).
  // lane covers row +(lane>>4), LDS slot byte x=(lane&15)*16; global col byte
  // is the swizzled x ^ ((row&7)<<4)  (so LDS[row][x] = G[row][x^swz]).
  size_t gsrc[4];   // per-lane global f32 index (chunk-invariant part)
  int lofs[4];      // wave-uniform LDS f32 offset of the inst base
#pragma unroll
  for (int j = 0; j < 4; ++j) {
    const int row = (wave * 4 + j) * 4 + (lane >> 4);
    const int colb = ((lane & 15) << 4) ^ ((row & 7) << 4);   // byte in [0,256)
    gsrc[j] = (size_t)(bm0 + row) * CDIM + (colb >> 2);
    lofs[j] = (wave * 4 + j) * 256;
  }

  // ---- read geometry: A-frag row = wave*16+c; nominal 32B at ks*128+g*32,
  // read as two 16B pieces, each XOR'd with the row swizzle.
  const int arow = wave * 16 + c;
  const int aswz = (arow & 7) << 4;
  int ra0[2], ra1[2];   // byte offsets into the chunk buffer
#pragma unroll
  for (int ks = 0; ks < 2; ++ks) {
    const int ncol = ks * 128 + g * 32;
    ra0[ks] = arow * 256 + ((ncol) ^ aswz);
    ra1[ks] = arow * 256 + ((ncol + 16) ^ aswz);
  }

  f32x4 acc[4];
#pragma unroll
  for (int n = 0; n < 4; ++n) acc[n] = (f32x4){0.f, 0.f, 0.f, 0.f};

  auto stage = [&](int buf, int ch) {
    const float* __restrict__ eb = emb + (size_t)ch * PKCH;
    float* lb = &Abuf[buf][0];
#pragma unroll
    for (int j = 0; j < 4; ++j) {
      __builtin_amdgcn_global_load_lds(
          (const __attribute__((address_space(1))) void*)(uintptr_t)(eb + gsrc[j]),
          (__attribute__((address_space(3))) void*)(unsigned)(uintptr_t)(lb + lofs[j]),
          16, 0, 0);
    }
  };

  stage(0, 0);
  __syncthreads();   // drain prologue staging

  for (int ch = 0; ch < PNCH; ++ch) {
    if (ch + 1 < PNCH) stage((ch + 1) & 1, ch + 1);   // fire-and-forget prefetch
    // compute chunk ch from Abuf[ch&1]
    const char* base = (const char*)&Abuf[ch & 1][0];
    const __bf16* __restrict__ wp = W + (size_t)ch * PKCH + g * 8;
#pragma unroll
    for (int ks = 0; ks < 2; ++ks) {
      f32x4 lo = *(const f32x4*)(base + ra0[ks]);
      f32x4 hi = *(const f32x4*)(base + ra1[ks]);
      bf16x8 af;
      af[0] = (__bf16)lo[0];
      af[1] = (__bf16)lo[1];
      af[2] = (__bf16)lo[2];
      af[3] = (__bf16)lo[3];
      af[4] = (__bf16)hi[0];
      af[5] = (__bf16)hi[1];
      af[6] = (__bf16)hi[2];
      af[7] = (__bf16)hi[3];
#pragma unroll
      for (int n = 0; n < 4; ++n) {
        bf16x8 wf = *(const bf16x8*)(wp + (size_t)(n * 16 + c) * CDIM + ks * 32);
        acc[n] = __builtin_amdgcn_mfma_f32_16x16x32_bf16(af, wf, acc[n], 0, 0, 0);
      }
    }
    __syncthreads();   // drains stage(ch+1) loads; guards buffer reuse
  }

  // C/D layout: col = lane&15 (=c -> n*16+c), row = (lane>>4)*4 + reg (= m0+4g+r)
  if (pid < 2) {
    __bf16* __restrict__ dst = (pid == 0) ? Qo : Ko;
#pragma unroll
    for (int n = 0; n < 4; ++n)
#pragma unroll
      for (int r = 0; r < 4; ++r)
        dst[(size_t)(m0 + g * 4 + r) * DHEAD + n * 16 + c] = (__bf16)acc[n][r];
  } else {
    // Vt[b][v][t]: regs 0..3 are 4 consecutive t -> pack one 8B store
    const int t0 = m0 + g * 4;
    const int bb = t0 >> 12;        // 4096 rows per batch, blocks never straddle
    const int tl = t0 & (TSEQ - 1);
#pragma unroll
    for (int n = 0; n < 4; ++n) {
      const int v = n * 16 + c;
      ushort4 pk;
      pk.x = __builtin_bit_cast(unsigned short, (__bf16)acc[n][0]);
      pk.y = __builtin_bit_cast(unsigned short, (__bf16)acc[n][1]);
      pk.z = __builtin_bit_cast(unsigned short, (__bf16)acc[n][2]);
      pk.w = __builtin_bit_cast(unsigned short, (__bf16)acc[n][3]);
      *(ushort4*)(Vto + ((size_t)bb * DHEAD + v) * TSEQ + tl) = pk;
    }
  }
}

// ---------------- Causal flash attention, static-max softmax ----------------
// One block = 16 q-rows, 8 waves split the s-tiles; two independent s-tile
// chains per iteration (st, st+8) for in-wave ILP. (r3; attn ~80us.)
// Static m=0 is safe: |scores| < ~1 after 1/32 scale, exp2 cannot overflow.
// Row-sum l computed with a ones-vector MFMA (lands in same C-layout rows as O).
// OUTPUT IS FLOAT32 (reference output dtype).
#define NWAVE 8

__global__ __launch_bounds__(512) void attn_kernel(
    const __bf16* __restrict__ Q, const __bf16* __restrict__ K,
    const __bf16* __restrict__ Vt, float* __restrict__ out)
{
  __shared__ __bf16 Plds[NWAVE][16][72];   // per-wave P (C-layout -> A-layout round trip)
  __shared__ float Om[NWAVE][16][65];      // per-wave partial O for the merge
  __shared__ float La[NWAVE][16];          // per-wave partial row-sums

  const int b = blockIdx.y;
  const int tile = (int)gridDim.x - 1 - (int)blockIdx.x;  // big tiles first
  const int q0 = tile * 16;
  const int wave = threadIdx.x >> 6;
  const int lane = threadIdx.x & 63;
  const int g = lane >> 4, c = lane & 15;

  const __bf16* Qb = Q + (size_t)b * TSEQ * DHEAD;
  const __bf16* Kb = K + (size_t)b * TSEQ * DHEAD;
  const __bf16* Vb = Vt + (size_t)b * DHEAD * TSEQ;

  bf16x8 aq0 = *(const bf16x8*)(Qb + (size_t)(q0 + c) * DHEAD + g * 8);
  bf16x8 aq1 = *(const bf16x8*)(Qb + (size_t)(q0 + c) * DHEAD + 32 + g * 8);

  bf16x8 ones;
#pragma unroll
  for (int j = 0; j < 8; ++j) ones[j] = (__bf16)1.0f;

  f32x4 o[4];
#pragma unroll
  for (int n = 0; n < 4; ++n) o[n] = (f32x4){0.f, 0.f, 0.f, 0.f};
  f32x4 lacc = (f32x4){0.f, 0.f, 0.f, 0.f};

  const float kScale = 0.04508422f;  // (1/32) * log2(e)
  const int nt = (q0 + 16 + 63) >> 6;

  for (int st = wave; st < nt; st += 2 * NWAVE) {
    const int s0A = st * 64;
    const int stB = st + NWAVE;
    const bool hasB = stB < nt;              // wave-uniform
    const int s0B = stB * 64;

    // ---- issue BOTH chains' K loads up front (16 loads in flight) ----
    bf16x8 ka0[4], ka1[4], kb0[4], kb1[4];
#pragma unroll
    for (int n = 0; n < 4; ++n) {
      const __bf16* kp = Kb + (size_t)(s0A + n * 16 + c) * DHEAD + g * 8;
      ka0[n] = *(const bf16x8*)(kp);
      ka1[n] = *(const bf16x8*)(kp + 32);
    }
    if (hasB) {
#pragma unroll
      for (int n = 0; n < 4; ++n) {
        const __bf16* kp = Kb + (size_t)(s0B + n * 16 + c) * DHEAD + g * 8;
        kb0[n] = *(const bf16x8*)(kp);
        kb1[n] = *(const bf16x8*)(kp + 32);
      }
    }

    // ---- chain A: QK ----
    f32x4 sA[4];
#pragma unroll
    for (int n = 0; n < 4; ++n) {
      f32x4 z = (f32x4){0.f, 0.f, 0.f, 0.f};
      z = __builtin_amdgcn_mfma_f32_16x16x32_bf16(aq0, ka0[n], z, 0, 0, 0);
      sA[n] = __builtin_amdgcn_mfma_f32_16x16x32_bf16(aq1, ka1[n], z, 0, 0, 0);
    }
    // ---- hoisted V loads A (latency hides under exp/DS below) ----
    bf16x8 va0[4], va1[4];
#pragma unroll
    for (int n = 0; n < 4; ++n) {
      const __bf16* vp = Vb + (size_t)(n * 16 + c) * TSEQ + s0A + g * 8;
      va0[n] = *(const bf16x8*)(vp);
      va1[n] = *(const bf16x8*)(vp + 32);
    }
    // ---- exp + DS-write A ----
#pragma unroll
    for (int n = 0; n < 4; ++n) {
      const int sidx = s0A + n * 16 + c;
#pragma unroll
      for (int r = 0; r < 4; ++r) {
        const int qidx = q0 + g * 4 + r;
        float p = (sidx <= qidx) ? __builtin_amdgcn_exp2f(sA[n][r] * kScale) : 0.f;
        Plds[wave][g * 4 + r][n * 16 + c] = (__bf16)p;
      }
    }

    // ---- chain B: QK (K arrived while A ran) + hoisted V loads B ----
    f32x4 sB[4];
    bf16x8 vb0[4], vb1[4];
    if (hasB) {
#pragma unroll
      for (int n = 0; n < 4; ++n) {
        f32x4 z = (f32x4){0.f, 0.f, 0.f, 0.f};
        z = __builtin_amdgcn_mfma_f32_16x16x32_bf16(aq0, kb0[n], z, 0, 0, 0);
        sB[n] = __builtin_amdgcn_mfma_f32_16x16x32_bf16(aq1, kb1[n], z, 0, 0, 0);
      }
#pragma unroll
      for (int n = 0; n < 4; ++n) {
        const __bf16* vp = Vb + (size_t)(n * 16 + c) * TSEQ + s0B + g * 8;
        vb0[n] = *(const bf16x8*)(vp);
        vb1[n] = *(const bf16x8*)(vp + 32);
      }
    }

    // ---- DS-read A, rowsum A ----
    bf16x8 p0A = *(const bf16x8*)(&Plds[wave][c][g * 8]);
    bf16x8 p1A = *(const bf16x8*)(&Plds[wave][c][32 + g * 8]);
    lacc = __builtin_amdgcn_mfma_f32_16x16x32_bf16(p0A, ones, lacc, 0, 0, 0);
    lacc = __builtin_amdgcn_mfma_f32_16x16x32_bf16(p1A, ones, lacc, 0, 0, 0);

    // ---- exp + DS-write B (aliases A's reads -> ordered after them) ----
    if (hasB) {
#pragma unroll
      for (int n = 0; n < 4; ++n) {
        const int sidx = s0B + n * 16 + c;
#pragma unroll
        for (int r = 0; r < 4; ++r) {
          const int qidx = q0 + g * 4 + r;
          float p = (sidx <= qidx) ? __builtin_amdgcn_exp2f(sB[n][r] * kScale) : 0.f;
          Plds[wave][g * 4 + r][n * 16 + c] = (__bf16)p;
        }
      }
    }

    // ---- PV A (V arrived during exp/DS) ----
#pragma unroll
    for (int n = 0; n < 4; ++n) {
      o[n] = __builtin_amdgcn_mfma_f32_16x16x32_bf16(p0A, va0[n], o[n], 0, 0, 0);
      o[n] = __builtin_amdgcn_mfma_f32_16x16x32_bf16(p1A, va1[n], o[n], 0, 0, 0);
    }

    // ---- DS-read B, rowsum B, PV B ----
    if (hasB) {
      bf16x8 p0B = *(const bf16x8*)(&Plds[wave][c][g * 8]);
      bf16x8 p1B = *(const bf16x8*)(&Plds[wave][c][32 + g * 8]);
      lacc = __builtin_amdgcn_mfma_f32_16x16x32_bf16(p0B, ones, lacc, 0, 0, 0);
      lacc = __builtin_amdgcn_mfma_f32_16x16x32_bf16(p1B, ones, lacc, 0, 0, 0);
#pragma unroll
      for (int n = 0; n < 4; ++n) {
        o[n] = __builtin_amdgcn_mfma_f32_16x16x32_bf16(p0B, vb0[n], o[n], 0, 0, 0);
        o[n] = __builtin_amdgcn_mfma_f32_16x16x32_bf16(p1B, vb1[n], o[n], 0, 0, 0);
      }
    }
  }

  // write per-wave partials (static max => plain sums merge)
#pragma unroll
  for (int n = 0; n < 4; ++n)
#pragma unroll
    for (int r = 0; r < 4; ++r)
      Om[wave][g * 4 + r][n * 16 + c] = o[n][r];
  if (c == 0) {
#pragma unroll
    for (int r = 0; r < 4; ++r) La[wave][g * 4 + r] = lacc[r];
  }
  __syncthreads();

  // f32 output: 512 threads x (1 row x 2 cols) = 16 rows x 64 cols
  const int tid = threadIdx.x;
  const int q = tid >> 5;
  const int c2 = (tid & 31) * 2;
  float l = 0.f;
#pragma unroll
  for (int w = 0; w < NWAVE; ++w) l += La[w][q];
  float s0 = 0.f, s1 = 0.f;
#pragma unroll
  for (int w = 0; w < NWAVE; ++w) {
    s0 += Om[w][q][c2];
    s1 += Om[w][q][c2 + 1];
  }
  const float inv = 1.0f / l;
  float2 r;
  r.x = s0 * inv;
  r.y = s1 * inv;
  *(float2*)(out + ((size_t)b * TSEQ + q0 + q) * DHEAD + c2) = r;
}

extern "C" void kernel_launch(void* const* d_in, const int* in_sizes, int n_in,
                              void* d_out, int out_size, void* d_ws, size_t ws_size,
                              hipStream_t stream) {
  const float* qe = (const float*)d_in[0];
  const float* ke = (const float*)d_in[1];
  const float* ve = (const float*)d_in[2];
  const float* wq = (const float*)d_in[3];
  const float* wk = (const float*)d_in[4];
  const float* wv = (const float*)d_in[5];

  __bf16* Qw  = (__bf16*)d_ws;
  __bf16* Kw  = Qw + (size_t)4 * TSEQ * DHEAD;
  __bf16* Vtw = Kw + (size_t)4 * TSEQ * DHEAD;
  __bf16* Wb  = Vtw + (size_t)4 * TSEQ * DHEAD;   // 3*64*1024 bf16 = 384KB

  wconv_kernel<<<dim3(96), dim3(256), 0, stream>>>(wq, wk, wv, Wb);

  dim3 g1(4 * TSEQ / 64, 3), b1(256);
  proj_kernel<<<g1, b1, 0, stream>>>(qe, ke, ve, Wb, Qw, Kw, Vtw);

  dim3 g2(TSEQ / 16, 4), b2(512);
  attn_kernel<<<g2, b2, 0, stream>>>(Qw, Kw, Vtw, (float*)d_out);
}